// Round 9
// baseline (419.224 us; speedup 1.0000x reference)
//
#include <hip/hip_runtime.h>
#include <hip/hip_bf16.h>
#include <stdint.h>

#define Bb   512
#define Tt   2048
#define Dd   32
#define Ee   64
#define Kk   8
#define OUTn 1024

typedef __attribute__((ext_vector_type(4))) float f32x4;
typedef __attribute__((ext_vector_type(8))) short short8;
typedef __attribute__((ext_vector_type(4))) unsigned int uint4v;

static __device__ __forceinline__ uint32_t f2bf(float f) {
  // round-to-nearest-even f32 -> bf16 bits (bit-identical to R1..R8 passing runs)
  uint32_t u = __float_as_uint(f);
  return (u + 0x7FFFu + ((u >> 16) & 1u)) >> 16;
}
static __device__ __forceinline__ uint32_t umax32(uint32_t a, uint32_t b){ return a > b ? a : b; }
static __device__ __forceinline__ uint32_t umin32(uint32_t a, uint32_t b){ return a < b ? a : b; }

// ---------------------------------------------------------------------------
// Kernel A v7: DRAM-contiguity-first. R1-R8 invariant: gumbel staged in
// 128-256B row-fragments -> ~10^5 streams touching 1-2 DRAM lines per row
// activation -> 1.1-1.8 TB/s ceiling (probe with 1KB-contiguous instrs and
// sequential walk: 2.7 TB/s). Fix: every gumbel gll instr = 1KB contiguous
// of ONE expert row; rows touched in 2KB chunks.
// Block = 4 waves (grid 512 = b). Wave w: experts w*16..+15 x all 2048 t.
// Slab [16 e][512 t] f32 = 32 KB/wave, single-buffered with half-slab
// pipelining: {wait vmcnt(16); compute 256-token half; issue next 16x1KB gll}
// -> 16-32KB always in flight, waits never reach 0 mid-loop. x read per-lane
// f32x4 (2KB contiguous per mfma; 4 waves read same stream -> L1 dedupe;
// positional waits on these drain only already-landed older batches).
// 4 waves/CU (135KB LDS, 1 block/CU) is intentional: pure streaming needs
// MLP (64KB in flight >> 4KB required), not TLP.
// Per-lane sort depth 7 (class-overflow P ~1e-4/run vs 1.6e-2 at depth 6),
// top-16 extraction -> f64 rescore -> exact top-8 -> gather (validated tail).
// log-softmax skipped: per-(b,e)-constant shifts can't change ordering.
// ---------------------------------------------------------------------------
__global__ __launch_bounds__(256) void kA_select(
    const float* __restrict__ x,        // [B,T,D]
    const float* __restrict__ gate_w,   // [E,D]
    const float* __restrict__ gumbel,   // [B,E,T]
    uint16_t* __restrict__ inp)         // ws: [B,E,K*D] bf16 bits
{
  const int b    = blockIdx.x;
  const int tid  = threadIdx.x;
  const int wave = tid >> 6;
  const int lane = tid & 63;
  const int l15  = lane & 15;
  const int l4   = lane >> 4;

  __shared__ __attribute__((aligned(16))) float gbuf[4][16 * 512]; // 128 KB
  __shared__ uint32_t cand[Ee][16];                                //   4 KB

  // A-frag: gw[wave*16 + l15][l4*8 + j]
  short8 gfrag;
  {
    const float* gp = gate_w + (size_t)(wave * 16 + l15) * Dd + l4 * 8;
    f32x4 g0 = *(const f32x4*)(gp);
    f32x4 g1 = *(const f32x4*)(gp + 4);
    gfrag[0] = (short)f2bf(g0[0]); gfrag[1] = (short)f2bf(g0[1]);
    gfrag[2] = (short)f2bf(g0[2]); gfrag[3] = (short)f2bf(g0[3]);
    gfrag[4] = (short)f2bf(g1[0]); gfrag[5] = (short)f2bf(g1[1]);
    gfrag[6] = (short)f2bf(g1[2]); gfrag[7] = (short)f2bf(g1[3]);
  }

  // per-lane sorted top-7 keys per slot (slot r -> expert wave*16 + l4*4 + r)
  // key = (monotone_f32 & ~0x7FF) | (2047 - t)   (ties -> lower t wins)
  uint32_t s[4][7];
  #pragma unroll
  for (int r = 0; r < 4; ++r)
    #pragma unroll
    for (int j = 0; j < 7; ++j) s[r][j] = 0u;

  const float* grow = gumbel + ((size_t)b * Ee + wave * 16) * Tt + lane * 4;
  const float* xrow = x + ((size_t)b * Tt + l15) * Dd + l4 * 8;

  // stage one half-slab: 16 x gll(16B) -- each 1 KB contiguous of one row;
  // successive halves touch each row in 2 KB chunks.
  auto stageH = [&](int S, int half) {
    #pragma unroll
    for (int e = 0; e < 16; ++e) {
      const float* src = grow + (size_t)e * Tt + S * 512 + half * 256;
      float* dst = &gbuf[wave][e * 512 + half * 256];   // wave-uniform base
      __builtin_amdgcn_global_load_lds(
          (const __attribute__((address_space(1))) void*)src,
          (__attribute__((address_space(3))) void*)dst, 16, 0, 0);
    }
  };

  // compute one 256-token half: 16 mfmas
  auto computeH = [&](int S, int half) {
    #pragma unroll
    for (int g = 0; g < 16; ++g) {
      const int tglob = S * 512 + half * 256 + g * 16;    // + l15 per lane
      const float* xp = xrow + (size_t)tglob * Dd;
      f32x4 x0 = *(const f32x4*)(xp);
      f32x4 x1 = *(const f32x4*)(xp + 4);
      short8 bfr;
      bfr[0] = (short)f2bf(x0[0]); bfr[1] = (short)f2bf(x0[1]);
      bfr[2] = (short)f2bf(x0[2]); bfr[3] = (short)f2bf(x0[3]);
      bfr[4] = (short)f2bf(x1[0]); bfr[5] = (short)f2bf(x1[1]);
      bfr[6] = (short)f2bf(x1[2]); bfr[7] = (short)f2bf(x1[3]);
      f32x4 acc = {0.f, 0.f, 0.f, 0.f};
      acc = __builtin_amdgcn_mfma_f32_16x16x32_bf16(gfrag, bfr, acc, 0, 0, 0);
      const uint32_t tl = 2047u - (uint32_t)(tglob + l15);
      #pragma unroll
      for (int r = 0; r < 4; ++r) {
        float gv = gbuf[wave][(l4 * 4 + r) * 512 + half * 256 + g * 16 + l15];
        float sc = acc[r] + gv;
        uint32_t u = __float_as_uint(sc);
        u = (u & 0x80000000u) ? ~u : (u | 0x80000000u);  // monotone total order
        uint32_t key = (u & 0xFFFFF800u) | tl;
        uint32_t cc = umax32(s[r][6], key);
        uint32_t dd;
        dd = s[r][5]; s[r][6] = umin32(dd, cc); cc = umax32(dd, cc);
        dd = s[r][4]; s[r][5] = umin32(dd, cc); cc = umax32(dd, cc);
        dd = s[r][3]; s[r][4] = umin32(dd, cc); cc = umax32(dd, cc);
        dd = s[r][2]; s[r][3] = umin32(dd, cc); cc = umax32(dd, cc);
        dd = s[r][1]; s[r][2] = umin32(dd, cc); cc = umax32(dd, cc);
        dd = s[r][0]; s[r][1] = umin32(dd, cc); s[r][0] = umax32(dd, cc);
      }
    }
  };

  // ---- main loop: per-wave half-slab pipeline, counted vmcnt, no barriers ----
  stageH(0, 0);
  stageH(0, 1);                                   // 32 in flight
  #pragma unroll 1
  for (int S = 0; S < 4; ++S) {
    asm volatile("s_waitcnt vmcnt(16)" ::: "memory");   // half A landed
    __builtin_amdgcn_sched_barrier(0);
    computeH(S, 0);
    __builtin_amdgcn_sched_barrier(0);
    if (S < 3) stageH(S + 1, 0);                  // overwrite tokens 0..255 (reads done)
    if (S < 3) asm volatile("s_waitcnt vmcnt(16)" ::: "memory");  // half B landed
    else       asm volatile("s_waitcnt vmcnt(0)"  ::: "memory");
    __builtin_amdgcn_sched_barrier(0);
    computeH(S, 1);
    __builtin_amdgcn_sched_barrier(0);
    if (S < 3) stageH(S + 1, 1);
  }

  // ---- extract per-expert top-16 across the 16 lanes of each l4-group ----
  #pragma unroll
  for (int r = 0; r < 4; ++r) {
    const int e_abs = wave * 16 + l4 * 4 + r;
    #pragma unroll
    for (int rnd = 0; rnd < 16; ++rnd) {
      uint32_t cur = s[r][0];
      uint32_t mx = cur;
      mx = umax32(mx, (uint32_t)__shfl_xor((int)mx, 1));
      mx = umax32(mx, (uint32_t)__shfl_xor((int)mx, 2));
      mx = umax32(mx, (uint32_t)__shfl_xor((int)mx, 4));
      mx = umax32(mx, (uint32_t)__shfl_xor((int)mx, 8));
      if (l15 == rnd) cand[e_abs][rnd] = mx;
      const bool pop = (cur == mx);   // keys unique (t embedded) -> one lane pops
      s[r][0] = pop ? s[r][1] : s[r][0];
      s[r][1] = pop ? s[r][2] : s[r][1];
      s[r][2] = pop ? s[r][3] : s[r][2];
      s[r][3] = pop ? s[r][4] : s[r][3];
      s[r][4] = pop ? s[r][5] : s[r][4];
      s[r][5] = pop ? s[r][6] : s[r][5];
      s[r][6] = pop ? 0u      : s[r][6];
    }
  }
  __syncthreads();   // the only block-wide barrier

  // ---- per expert (16 per wave): f64 rescore of 16 candidates, top-8, gather ----
  #pragma unroll 1
  for (int el = 0; el < 16; ++el) {
    const int e = wave * 16 + el;
    const bool alive = lane < 16;
    uint32_t myT = 2047;
    double v = -1e300;
    if (alive) {
      uint32_t key = cand[e][lane];
      myT = 2047u - (key & 2047u);
      const float* xr = x + ((size_t)b * Tt + myT) * Dd;
      const float* gr = gate_w + (size_t)e * Dd;
      double a = 0.0;
      #pragma unroll
      for (int d = 0; d < Dd; ++d) a += (double)xr[d] * (double)gr[d];
      v = a + (double)gumbel[((size_t)b * Ee + e) * Tt + myT];
    }
    uint32_t ti = alive ? myT : 0xFFFFu;
    uint32_t ord[8];
    #pragma unroll
    for (int k = 0; k < 8; ++k) {
      double bv = v; uint32_t bt = ti;
      #pragma unroll
      for (int off = 1; off < 64; off <<= 1) {
        double   ov = __shfl_xor(bv, off);
        uint32_t ot = (uint32_t)__shfl_xor((int)bt, off);
        if (ov > bv || (ov == bv && ot < bt)) { bv = ov; bt = ot; }
      }
      ord[k] = bt;           // uniform across lanes
      if (ti == bt) v = -1e300;
    }

    // gather: wave writes inp[b][e][0..255] (8 tokens x 32 feats, bf16)
    const int kk = lane >> 3, sub = lane & 7;
    uint32_t tk = ord[0];
    #pragma unroll
    for (int qq = 1; qq < 8; ++qq) tk = (kk == qq) ? ord[qq] : tk;
    const float* xs = x + ((size_t)b * Tt + tk) * Dd + sub * 4;
    f32x4 xv = *(const f32x4*)xs;
    uint32_t p0 = f2bf(xv[0]) | (f2bf(xv[1]) << 16);
    uint32_t p1 = f2bf(xv[2]) | (f2bf(xv[3]) << 16);
    uint32_t* dst = (uint32_t*)inp + ((((size_t)b * Ee + e) * 256) + kk * 32 + sub * 4) / 2;
    dst[0] = p0; dst[1] = p1;
  }
}

// ---------------------------------------------------------------------------
// Kernel B: grouped per-expert GEMM  out[b,e,:] = inp[b,e,:] . W[e]^T + bias
// 128x128 tile, K=256 in 4 steps, bf16 MFMA, W converted f32->bf16 in staging.
// XCD-aware decode: expert e's 32 blocks all land on XCD e/8 -> W slices hit L2.
// ---------------------------------------------------------------------------
__global__ __launch_bounds__(256) void kB_gemm(
    const uint16_t* __restrict__ inp,      // [B,E,256] bf16 bits
    const float* __restrict__ expert_w,    // [E,OUT,256]
    const float* __restrict__ expert_b,    // [E,OUT]
    float* __restrict__ out)               // [B,E,OUT]
{
  const int bid = blockIdx.x;                // 2048 blocks
  const int xcd = bid & 7;
  const int idx = bid >> 3;                  // 0..255
  const int e   = xcd * 8 + (idx >> 5);      // 8 experts per XCD
  const int rem = idx & 31;
  const int mb  = rem >> 3;
  const int nb  = rem & 7;
  const int b0 = mb * 128;
  const int o0 = nb * 128;
  const int tid  = threadIdx.x;
  const int wave = tid >> 6;
  const int lane = tid & 63;
  const int l15 = lane & 15, l4 = lane >> 4;
  const int wm = (wave & 1) * 64;
  const int wn = (wave >> 1) * 64;

  __shared__ __attribute__((aligned(16))) uint32_t Al[128 * 32]; // [m][64 bf16] swizzled
  __shared__ __attribute__((aligned(16))) uint32_t Wl[128 * 32]; // [o][64 bf16] swizzled

  f32x4 acc[4][4];
  #pragma unroll
  for (int i = 0; i < 4; ++i)
    #pragma unroll
    for (int j = 0; j < 4; ++j) acc[i][j] = (f32x4){0.f, 0.f, 0.f, 0.f};

  for (int ks = 0; ks < 4; ++ks) {
    // stage A (already bf16): 128 rows x 64k
    #pragma unroll
    for (int i = 0; i < 4; ++i) {
      int gi = tid + i * 256;
      int m = gi >> 3, qq = gi & 7;
      const uint4v* src = (const uint4v*)(inp + ((size_t)(b0 + m) * Ee + e) * 256 + ks * 64 + qq * 8);
      *(uint4v*)&Al[m * 32 + ((qq ^ (m & 7)) * 4)] = *src;
    }
    // stage W with f32 -> bf16 conversion
    #pragma unroll
    for (int i = 0; i < 4; ++i) {
      int gi = tid + i * 256;
      int o = gi >> 3, qq = gi & 7;
      const float* src = expert_w + ((size_t)e * OUTn + o0 + o) * 256 + ks * 64 + qq * 8;
      f32x4 w0 = *(const f32x4*)src;
      f32x4 w1 = *(const f32x4*)(src + 4);
      uint4v v;
      v[0] = f2bf(w0[0]) | (f2bf(w0[1]) << 16);
      v[1] = f2bf(w0[2]) | (f2bf(w0[3]) << 16);
      v[2] = f2bf(w1[0]) | (f2bf(w1[1]) << 16);
      v[3] = f2bf(w1[2]) | (f2bf(w1[3]) << 16);
      *(uint4v*)&Wl[o * 32 + ((qq ^ (o & 7)) * 4)] = v;
    }
    __syncthreads();

    short8 af[4][2], bf[4][2];
    #pragma unroll
    for (int mf = 0; mf < 4; ++mf)
      #pragma unroll
      for (int kb = 0; kb < 2; ++kb) {
        int row = wm + mf * 16 + l15;
        int g = kb * 4 + l4;
        af[mf][kb] = *(const short8*)&Al[row * 32 + ((g ^ (row & 7)) * 4)];
      }
    #pragma unroll
    for (int nf = 0; nf < 4; ++nf)
      #pragma unroll
      for (int kb = 0; kb < 2; ++kb) {
        int row = wn + nf * 16 + l15;
        int g = kb * 4 + l4;
        bf[nf][kb] = *(const short8*)&Wl[row * 32 + ((g ^ (row & 7)) * 4)];
      }
    #pragma unroll
    for (int mf = 0; mf < 4; ++mf)
      #pragma unroll
      for (int nf = 0; nf < 4; ++nf)
        #pragma unroll
        for (int kb = 0; kb < 2; ++kb)
          acc[mf][nf] = __builtin_amdgcn_mfma_f32_16x16x32_bf16(af[mf][kb], bf[nf][kb], acc[mf][nf], 0, 0, 0);
    __syncthreads();
  }

  // epilogue: D col = lane&15 -> o, row = (lane>>4)*4+reg -> b-row
  #pragma unroll
  for (int nf = 0; nf < 4; ++nf) {
    const int ocol = o0 + wn + nf * 16 + l15;
    const float bias = expert_b[(size_t)e * OUTn + ocol];
    #pragma unroll
    for (int mf = 0; mf < 4; ++mf) {
      #pragma unroll
      for (int reg = 0; reg < 4; ++reg) {
        const int mrow = b0 + wm + mf * 16 + l4 * 4 + reg;
        out[((size_t)mrow * Ee + e) * OUTn + ocol] = acc[mf][nf][reg] + bias;
      }
    }
  }
}

extern "C" void kernel_launch(void* const* d_in, const int* in_sizes, int n_in,
                              void* d_out, int out_size, void* d_ws, size_t ws_size,
                              hipStream_t stream) {
  const float* x        = (const float*)d_in[0];
  const float* gate_w   = (const float*)d_in[1];
  // d_in[2] = gate_b: constant per expert -> cannot change per-(b,e) top-k
  // ordering over tokens (and is zeros); values are never used downstream.
  const float* expert_w = (const float*)d_in[3];
  const float* expert_b = (const float*)d_in[4];
  const float* gumbel   = (const float*)d_in[5];

  uint16_t* inp = (uint16_t*)d_ws;   // 512*64*256*2 = 16.8 MB

  kA_select<<<Bb, 256, 0, stream>>>(x, gate_w, gumbel, inp);
  kB_gemm<<<2048, 256, 0, stream>>>(inp, expert_w, expert_b, (float*)d_out);
}

// Round 10
// 261.136 us; speedup vs baseline: 1.6054x; 1.6054x over previous
//
#include <hip/hip_runtime.h>
#include <hip/hip_bf16.h>
#include <stdint.h>

#define Bb   512
#define Tt   2048
#define Dd   32
#define Ee   64
#define Kk   8
#define OUTn 1024

typedef __attribute__((ext_vector_type(4))) float f32x4;
typedef __attribute__((ext_vector_type(8))) short short8;
typedef __attribute__((ext_vector_type(4))) unsigned int uint4v;

static __device__ __forceinline__ uint32_t f2bf(float f) {
  // round-to-nearest-even f32 -> bf16 bits (bit-identical to R1..R9 passing runs)
  uint32_t u = __float_as_uint(f);
  return (u + 0x7FFFu + ((u >> 16) & 1u)) >> 16;
}
static __device__ __forceinline__ uint32_t umax32(uint32_t a, uint32_t b){ return a > b ? a : b; }
static __device__ __forceinline__ uint32_t umin32(uint32_t a, uint32_t b){ return a < b ? a : b; }

// ---------------------------------------------------------------------------
// Kernel A v8: occupancy-first. Empirical law from R1-R9 + probe: achieved
// read BW ~= 0.33-0.6 GB/s PER RESIDENT WAVE (per-wave in-flight is HW-capped
// at ~1-2 requests), independent of staging mechanism (gll/register), chunk
// size, or vmcnt schedule. probe: 2.7 TB/s @32 waves/CU; R3/4: 1.5 @16;
// R6: 1.43 @14; R5: 1.0 @8; R9: 0.65 @4. So: NO pipelining, NO gll, NO asm --
// just 32 waves/CU and plain per-lane loads; TLP does all latency hiding.
// Grid 2048 x 256 thr = 8 blocks/CU exactly. Block = (b, 16-expert group),
// wave = those 16 experts x one 512-token quarter. Per 16-token step: 2x 1KB
// fully-coalesced x loads + 4x gumbel row loads (64B/segment, fully consumed)
// + 1 MFMA + branchless depth-7 sorted insert. ~55 VGPR (<=64 -> full occ).
// LDS = 3KB (cand only). XCD-swizzled bid decode: the 4 blocks sharing one
// b's x land on the same XCD slot -> L2 dedup of x.
// Tail: per-(e,quarter) top-12 (depth-7 cell-loss P~2e-4/run; T=12 quarter-
// overflow P~0.008/run) -> 48-cand f64 rescore -> exact top-8 -> gather.
// Scores bit-identical to R1-R9 (same MFMA, same RNE-bf16 inputs).
// log-softmax skipped: per-(b,e)-constant shift can't change ordering.
// ---------------------------------------------------------------------------
__global__ __launch_bounds__(256) void kA_select(
    const float* __restrict__ x,        // [B,T,D]
    const float* __restrict__ gate_w,   // [E,D]
    const float* __restrict__ gumbel,   // [B,E,T]
    uint16_t* __restrict__ inp)         // ws: [B,E,K*D] bf16 bits
{
  const int bid    = blockIdx.x;
  const int xcd    = bid & 7;
  const int within = bid >> 3;
  const int b      = xcd * 64 + (within >> 2);  // same-b blocks share XCD slot
  const int eg     = within & 3;                // expert group: eg*16 .. eg*16+15
  const int tid  = threadIdx.x;
  const int wave = tid >> 6;                    // token quarter q
  const int lane = tid & 63;
  const int l15  = lane & 15;
  const int l4   = lane >> 4;

  __shared__ uint32_t cand[16][48];             // 3 KB

  // A-frag: gw[eg*16 + l15][l4*8 + j]
  short8 gfrag;
  {
    const float* gp = gate_w + (size_t)(eg * 16 + l15) * Dd + l4 * 8;
    f32x4 g0 = *(const f32x4*)(gp);
    f32x4 g1 = *(const f32x4*)(gp + 4);
    gfrag[0] = (short)f2bf(g0[0]); gfrag[1] = (short)f2bf(g0[1]);
    gfrag[2] = (short)f2bf(g0[2]); gfrag[3] = (short)f2bf(g0[3]);
    gfrag[4] = (short)f2bf(g1[0]); gfrag[5] = (short)f2bf(g1[1]);
    gfrag[6] = (short)f2bf(g1[2]); gfrag[7] = (short)f2bf(g1[3]);
  }

  // per-lane sorted top-7 keys per slot (slot r -> expert eg*16 + l4*4 + r)
  // key = (monotone_f32 & ~0x7FF) | (2047 - t)   (ties -> lower t wins)
  uint32_t s[4][7];
  #pragma unroll
  for (int r = 0; r < 4; ++r)
    #pragma unroll
    for (int j = 0; j < 7; ++j) s[r][j] = 0u;

  const float* grow = gumbel + ((size_t)b * Ee + eg * 16 + l4 * 4) * Tt + wave * 512 + l15;
  const float* xq   = x + ((size_t)b * Tt + wave * 512 + l15) * Dd + l4 * 8;

  // ---- main loop: 32 steps x 16 tokens; no barriers, no pipelining ----
  #pragma unroll 1
  for (int g = 0; g < 32; ++g) {
    const float* xp = xq + (size_t)(g * 16) * Dd;
    f32x4 x0 = *(const f32x4*)(xp);
    f32x4 x1 = *(const f32x4*)(xp + 4);
    float G0 = grow[(size_t)0 * Tt + g * 16];
    float G1 = grow[(size_t)1 * Tt + g * 16];
    float G2 = grow[(size_t)2 * Tt + g * 16];
    float G3 = grow[(size_t)3 * Tt + g * 16];
    short8 bfr;
    bfr[0] = (short)f2bf(x0[0]); bfr[1] = (short)f2bf(x0[1]);
    bfr[2] = (short)f2bf(x0[2]); bfr[3] = (short)f2bf(x0[3]);
    bfr[4] = (short)f2bf(x1[0]); bfr[5] = (short)f2bf(x1[1]);
    bfr[6] = (short)f2bf(x1[2]); bfr[7] = (short)f2bf(x1[3]);
    f32x4 acc = {0.f, 0.f, 0.f, 0.f};
    acc = __builtin_amdgcn_mfma_f32_16x16x32_bf16(gfrag, bfr, acc, 0, 0, 0);
    const uint32_t tl = 2047u - (uint32_t)(wave * 512 + g * 16 + l15);
    float Gv[4] = {G0, G1, G2, G3};
    #pragma unroll
    for (int r = 0; r < 4; ++r) {
      float sc = acc[r] + Gv[r];
      uint32_t u = __float_as_uint(sc);
      u = (u & 0x80000000u) ? ~u : (u | 0x80000000u);  // monotone total order
      uint32_t key = (u & 0xFFFFF800u) | tl;
      uint32_t cc = umax32(s[r][6], key);
      uint32_t dd;
      dd = s[r][5]; s[r][6] = umin32(dd, cc); cc = umax32(dd, cc);
      dd = s[r][4]; s[r][5] = umin32(dd, cc); cc = umax32(dd, cc);
      dd = s[r][3]; s[r][4] = umin32(dd, cc); cc = umax32(dd, cc);
      dd = s[r][2]; s[r][3] = umin32(dd, cc); cc = umax32(dd, cc);
      dd = s[r][1]; s[r][2] = umin32(dd, cc); cc = umax32(dd, cc);
      dd = s[r][0]; s[r][1] = umin32(dd, cc); s[r][0] = umax32(dd, cc);
    }
  }

  // ---- extraction: per (expert, quarter) top-12 across each 16-lane group ----
  #pragma unroll
  for (int r = 0; r < 4; ++r) {
    const int e_loc = l4 * 4 + r;                 // 0..15 within block
    #pragma unroll
    for (int rnd = 0; rnd < 12; ++rnd) {
      uint32_t cur = s[r][0];
      uint32_t mx = cur;
      mx = umax32(mx, (uint32_t)__shfl_xor((int)mx, 1));
      mx = umax32(mx, (uint32_t)__shfl_xor((int)mx, 2));
      mx = umax32(mx, (uint32_t)__shfl_xor((int)mx, 4));
      mx = umax32(mx, (uint32_t)__shfl_xor((int)mx, 8));
      if (l15 == rnd) cand[e_loc][wave * 12 + rnd] = mx;
      const bool pop = (cur == mx);   // keys unique (t embedded) -> one lane pops
      s[r][0] = pop ? s[r][1] : s[r][0];
      s[r][1] = pop ? s[r][2] : s[r][1];
      s[r][2] = pop ? s[r][3] : s[r][2];
      s[r][3] = pop ? s[r][4] : s[r][3];
      s[r][4] = pop ? s[r][5] : s[r][4];
      s[r][5] = pop ? s[r][6] : s[r][5];
      s[r][6] = pop ? 0u      : s[r][6];
    }
  }
  __syncthreads();   // the only block-wide barrier

  // ---- per expert (4 per wave): f64 rescore of 48 candidates, top-8, gather ----
  #pragma unroll 1
  for (int el = 0; el < 4; ++el) {
    const int e_loc = wave * 4 + el;
    const int e     = eg * 16 + e_loc;
    const bool alive = lane < 48;
    uint32_t myT = 2047;
    double v = -1e300;
    if (alive) {
      uint32_t key = cand[e_loc][lane];
      myT = 2047u - (key & 2047u);
      const float* xr = x + ((size_t)b * Tt + myT) * Dd;
      const float* gr = gate_w + (size_t)e * Dd;
      double a = 0.0;
      #pragma unroll
      for (int d = 0; d < Dd; ++d) a += (double)xr[d] * (double)gr[d];
      v = a + (double)gumbel[((size_t)b * Ee + e) * Tt + myT];
    }
    uint32_t ti = alive ? myT : 0xFFFFu;
    uint32_t ord[8];
    #pragma unroll
    for (int k = 0; k < 8; ++k) {
      double bv = v; uint32_t bt = ti;
      #pragma unroll
      for (int off = 1; off < 64; off <<= 1) {
        double   ov = __shfl_xor(bv, off);
        uint32_t ot = (uint32_t)__shfl_xor((int)bt, off);
        if (ov > bv || (ov == bv && ot < bt)) { bv = ov; bt = ot; }
      }
      ord[k] = bt;           // uniform across lanes
      if (ti == bt) v = -1e300;
    }

    // gather: wave writes inp[b][e][0..255] (8 tokens x 32 feats, bf16)
    const int kk = lane >> 3, sub = lane & 7;
    uint32_t tk = ord[0];
    #pragma unroll
    for (int qq = 1; qq < 8; ++qq) tk = (kk == qq) ? ord[qq] : tk;
    const float* xs = x + ((size_t)b * Tt + tk) * Dd + sub * 4;
    f32x4 xv = *(const f32x4*)xs;
    uint32_t p0 = f2bf(xv[0]) | (f2bf(xv[1]) << 16);
    uint32_t p1 = f2bf(xv[2]) | (f2bf(xv[3]) << 16);
    uint32_t* dst = (uint32_t*)inp + ((((size_t)b * Ee + e) * 256) + kk * 32 + sub * 4) / 2;
    dst[0] = p0; dst[1] = p1;
  }
}

// ---------------------------------------------------------------------------
// Kernel B: grouped per-expert GEMM  out[b,e,:] = inp[b,e,:] . W[e]^T + bias
// 128x128 tile, K=256 in 4 steps, bf16 MFMA, W converted f32->bf16 in staging.
// XCD-aware decode: expert e's 32 blocks all land on XCD e/8 -> W slices hit L2.
// ---------------------------------------------------------------------------
__global__ __launch_bounds__(256) void kB_gemm(
    const uint16_t* __restrict__ inp,      // [B,E,256] bf16 bits
    const float* __restrict__ expert_w,    // [E,OUT,256]
    const float* __restrict__ expert_b,    // [E,OUT]
    float* __restrict__ out)               // [B,E,OUT]
{
  const int bid = blockIdx.x;                // 2048 blocks
  const int xcd = bid & 7;
  const int idx = bid >> 3;                  // 0..255
  const int e   = xcd * 8 + (idx >> 5);      // 8 experts per XCD
  const int rem = idx & 31;
  const int mb  = rem >> 3;
  const int nb  = rem & 7;
  const int b0 = mb * 128;
  const int o0 = nb * 128;
  const int tid  = threadIdx.x;
  const int wave = tid >> 6;
  const int lane = tid & 63;
  const int l15 = lane & 15, l4 = lane >> 4;
  const int wm = (wave & 1) * 64;
  const int wn = (wave >> 1) * 64;

  __shared__ __attribute__((aligned(16))) uint32_t Al[128 * 32]; // [m][64 bf16] swizzled
  __shared__ __attribute__((aligned(16))) uint32_t Wl[128 * 32]; // [o][64 bf16] swizzled

  f32x4 acc[4][4];
  #pragma unroll
  for (int i = 0; i < 4; ++i)
    #pragma unroll
    for (int j = 0; j < 4; ++j) acc[i][j] = (f32x4){0.f, 0.f, 0.f, 0.f};

  for (int ks = 0; ks < 4; ++ks) {
    // stage A (already bf16): 128 rows x 64k
    #pragma unroll
    for (int i = 0; i < 4; ++i) {
      int gi = tid + i * 256;
      int m = gi >> 3, qq = gi & 7;
      const uint4v* src = (const uint4v*)(inp + ((size_t)(b0 + m) * Ee + e) * 256 + ks * 64 + qq * 8);
      *(uint4v*)&Al[m * 32 + ((qq ^ (m & 7)) * 4)] = *src;
    }
    // stage W with f32 -> bf16 conversion
    #pragma unroll
    for (int i = 0; i < 4; ++i) {
      int gi = tid + i * 256;
      int o = gi >> 3, qq = gi & 7;
      const float* src = expert_w + ((size_t)e * OUTn + o0 + o) * 256 + ks * 64 + qq * 8;
      f32x4 w0 = *(const f32x4*)src;
      f32x4 w1 = *(const f32x4*)(src + 4);
      uint4v v;
      v[0] = f2bf(w0[0]) | (f2bf(w0[1]) << 16);
      v[1] = f2bf(w0[2]) | (f2bf(w0[3]) << 16);
      v[2] = f2bf(w1[0]) | (f2bf(w1[1]) << 16);
      v[3] = f2bf(w1[2]) | (f2bf(w1[3]) << 16);
      *(uint4v*)&Wl[o * 32 + ((qq ^ (o & 7)) * 4)] = v;
    }
    __syncthreads();

    short8 af[4][2], bf[4][2];
    #pragma unroll
    for (int mf = 0; mf < 4; ++mf)
      #pragma unroll
      for (int kb = 0; kb < 2; ++kb) {
        int row = wm + mf * 16 + l15;
        int g = kb * 4 + l4;
        af[mf][kb] = *(const short8*)&Al[row * 32 + ((g ^ (row & 7)) * 4)];
      }
    #pragma unroll
    for (int nf = 0; nf < 4; ++nf)
      #pragma unroll
      for (int kb = 0; kb < 2; ++kb) {
        int row = wn + nf * 16 + l15;
        int g = kb * 4 + l4;
        bf[nf][kb] = *(const short8*)&Wl[row * 32 + ((g ^ (row & 7)) * 4)];
      }
    #pragma unroll
    for (int mf = 0; mf < 4; ++mf)
      #pragma unroll
      for (int nf = 0; nf < 4; ++nf)
        #pragma unroll
        for (int kb = 0; kb < 2; ++kb)
          acc[mf][nf] = __builtin_amdgcn_mfma_f32_16x16x32_bf16(af[mf][kb], bf[nf][kb], acc[mf][nf], 0, 0, 0);
    __syncthreads();
  }

  // epilogue: D col = lane&15 -> o, row = (lane>>4)*4+reg -> b-row
  #pragma unroll
  for (int nf = 0; nf < 4; ++nf) {
    const int ocol = o0 + wn + nf * 16 + l15;
    const float bias = expert_b[(size_t)e * OUTn + ocol];
    #pragma unroll
    for (int mf = 0; mf < 4; ++mf) {
      #pragma unroll
      for (int reg = 0; reg < 4; ++reg) {
        const int mrow = b0 + wm + mf * 16 + l4 * 4 + reg;
        out[((size_t)mrow * Ee + e) * OUTn + ocol] = acc[mf][nf][reg] + bias;
      }
    }
  }
}

extern "C" void kernel_launch(void* const* d_in, const int* in_sizes, int n_in,
                              void* d_out, int out_size, void* d_ws, size_t ws_size,
                              hipStream_t stream) {
  const float* x        = (const float*)d_in[0];
  const float* gate_w   = (const float*)d_in[1];
  // d_in[2] = gate_b: constant per expert -> cannot change per-(b,e) top-k
  // ordering over tokens (and is zeros); values are never used downstream.
  const float* expert_w = (const float*)d_in[3];
  const float* expert_b = (const float*)d_in[4];
  const float* gumbel   = (const float*)d_in[5];

  uint16_t* inp = (uint16_t*)d_ws;   // 512*64*256*2 = 16.8 MB

  kA_select<<<2048, 256, 0, stream>>>(x, gate_w, gumbel, inp);
  kB_gemm<<<2048, 256, 0, stream>>>(inp, expert_w, expert_b, (float*)d_out);
}

// Round 11
// 248.145 us; speedup vs baseline: 1.6894x; 1.0524x over previous
//
#include <hip/hip_runtime.h>
#include <hip/hip_bf16.h>
#include <stdint.h>

#define Bb   512
#define Tt   2048
#define Dd   32
#define Ee   64
#define Kk   8
#define OUTn 1024

typedef __attribute__((ext_vector_type(4))) float f32x4;
typedef __attribute__((ext_vector_type(2))) float f32x2;
typedef __attribute__((ext_vector_type(8))) short short8;
typedef __attribute__((ext_vector_type(4))) unsigned int uint4v;

static __device__ __forceinline__ uint32_t f2bf(float f) {
  // round-to-nearest-even f32 -> bf16 bits (bit-identical to R1..R10 passing runs)
  uint32_t u = __float_as_uint(f);
  return (u + 0x7FFFu + ((u >> 16) & 1u)) >> 16;
}
static __device__ __forceinline__ uint32_t umax32(uint32_t a, uint32_t b){ return a > b ? a : b; }
static __device__ __forceinline__ uint32_t umin32(uint32_t a, uint32_t b){ return a < b ? a : b; }

// ---------------------------------------------------------------------------
// Kernel A v9: R10 (occupancy-first, no staging, no pipelining) with ONE
// change: gumbel accessed in FULL-128B-line segments instead of 64B halves.
// Two-factor BW model from R1-R10: BW = min(f(resident waves), g(segment
// size)). R9: perfect segments, 4 waves/CU -> 0.65 TB/s. R10: 32 waves/CU,
// 64B segments -> 1.51. Probe: 32 waves + 1KB segments -> 2.7. This round
// tests the missing cell: 32 waves + 128B segments.
// Mechanism: remap the MFMA token group of sub-step c (c=0,1) to tokens
// {m*32 + l15*2 + c} so gumbel loads become per-lane f32x2 -> each of the 4
// row-segments per instr is 16 lanes x 8B = 128B contiguous. Selection is
// order-independent, so any token->mfma-slot bijection is valid; B-frag,
// score add, and key id all use the same remapping (scores bit-identical).
// Everything else frozen from R10: grid 2048x256 (8 blocks/CU, 32 waves/CU),
// ~60 VGPR, LDS 3KB, XCD-swizzled decode, depth-7 per-lane sort, top-12 per
// (e,quarter) -> 48-cand f64 rescore -> exact top-8 -> gather.
// log-softmax skipped: per-(b,e)-constant shift can't change ordering.
// ---------------------------------------------------------------------------
__global__ __launch_bounds__(256) void kA_select(
    const float* __restrict__ x,        // [B,T,D]
    const float* __restrict__ gate_w,   // [E,D]
    const float* __restrict__ gumbel,   // [B,E,T]
    uint16_t* __restrict__ inp)         // ws: [B,E,K*D] bf16 bits
{
  const int bid    = blockIdx.x;
  const int xcd    = bid & 7;
  const int within = bid >> 3;
  const int b      = xcd * 64 + (within >> 2);  // same-b blocks share XCD slot
  const int eg     = within & 3;                // expert group: eg*16 .. eg*16+15
  const int tid  = threadIdx.x;
  const int wave = tid >> 6;                    // token quarter q
  const int lane = tid & 63;
  const int l15  = lane & 15;
  const int l4   = lane >> 4;

  __shared__ uint32_t cand[16][48];             // 3 KB

  // A-frag: gw[eg*16 + l15][l4*8 + j]
  short8 gfrag;
  {
    const float* gp = gate_w + (size_t)(eg * 16 + l15) * Dd + l4 * 8;
    f32x4 g0 = *(const f32x4*)(gp);
    f32x4 g1 = *(const f32x4*)(gp + 4);
    gfrag[0] = (short)f2bf(g0[0]); gfrag[1] = (short)f2bf(g0[1]);
    gfrag[2] = (short)f2bf(g0[2]); gfrag[3] = (short)f2bf(g0[3]);
    gfrag[4] = (short)f2bf(g1[0]); gfrag[5] = (short)f2bf(g1[1]);
    gfrag[6] = (short)f2bf(g1[2]); gfrag[7] = (short)f2bf(g1[3]);
  }

  // per-lane sorted top-7 keys per slot (slot r -> expert eg*16 + l4*4 + r)
  // key = (monotone_f32 & ~0x7FF) | (2047 - t)   (ties -> lower t wins)
  uint32_t s[4][7];
  #pragma unroll
  for (int r = 0; r < 4; ++r)
    #pragma unroll
    for (int j = 0; j < 7; ++j) s[r][j] = 0u;

  // lane (l4,l15) owns tokens {quarter + m*32 + l15*2 + c} for rows l4*4+r
  const float* grow = gumbel + ((size_t)b * Ee + eg * 16 + l4 * 4) * Tt + wave * 512 + l15 * 2;
  const float* xq   = x + ((size_t)b * Tt + wave * 512 + l15 * 2) * Dd + l4 * 8;

  // ---- main loop: 16 macro-steps x 32 tokens; no barriers, no pipelining ----
  #pragma unroll 1
  for (int m = 0; m < 16; ++m) {
    // gumbel: 4 instrs, each 4 row-segments of 128B (16 lanes x f32x2)
    f32x2 G0 = *(const f32x2*)(grow + (size_t)0 * Tt + m * 32);
    f32x2 G1 = *(const f32x2*)(grow + (size_t)1 * Tt + m * 32);
    f32x2 G2 = *(const f32x2*)(grow + (size_t)2 * Tt + m * 32);
    f32x2 G3 = *(const f32x2*)(grow + (size_t)3 * Tt + m * 32);
    #pragma unroll
    for (int c = 0; c < 2; ++c) {
      const float* xp = xq + (size_t)(m * 32 + c) * Dd;
      f32x4 x0 = *(const f32x4*)(xp);
      f32x4 x1 = *(const f32x4*)(xp + 4);
      short8 bfr;
      bfr[0] = (short)f2bf(x0[0]); bfr[1] = (short)f2bf(x0[1]);
      bfr[2] = (short)f2bf(x0[2]); bfr[3] = (short)f2bf(x0[3]);
      bfr[4] = (short)f2bf(x1[0]); bfr[5] = (short)f2bf(x1[1]);
      bfr[6] = (short)f2bf(x1[2]); bfr[7] = (short)f2bf(x1[3]);
      f32x4 acc = {0.f, 0.f, 0.f, 0.f};
      acc = __builtin_amdgcn_mfma_f32_16x16x32_bf16(gfrag, bfr, acc, 0, 0, 0);
      const uint32_t tl = 2047u - (uint32_t)(wave * 512 + m * 32 + l15 * 2 + c);
      float Gv[4] = {G0[c], G1[c], G2[c], G3[c]};
      #pragma unroll
      for (int r = 0; r < 4; ++r) {
        float sc = acc[r] + Gv[r];
        uint32_t u = __float_as_uint(sc);
        u = (u & 0x80000000u) ? ~u : (u | 0x80000000u);  // monotone total order
        uint32_t key = (u & 0xFFFFF800u) | tl;
        uint32_t cc = umax32(s[r][6], key);
        uint32_t dd;
        dd = s[r][5]; s[r][6] = umin32(dd, cc); cc = umax32(dd, cc);
        dd = s[r][4]; s[r][5] = umin32(dd, cc); cc = umax32(dd, cc);
        dd = s[r][3]; s[r][4] = umin32(dd, cc); cc = umax32(dd, cc);
        dd = s[r][2]; s[r][3] = umin32(dd, cc); cc = umax32(dd, cc);
        dd = s[r][1]; s[r][2] = umin32(dd, cc); cc = umax32(dd, cc);
        dd = s[r][0]; s[r][1] = umin32(dd, cc); s[r][0] = umax32(dd, cc);
      }
    }
  }

  // ---- extraction: per (expert, quarter) top-12 across each 16-lane group ----
  #pragma unroll
  for (int r = 0; r < 4; ++r) {
    const int e_loc = l4 * 4 + r;                 // 0..15 within block
    #pragma unroll
    for (int rnd = 0; rnd < 12; ++rnd) {
      uint32_t cur = s[r][0];
      uint32_t mx = cur;
      mx = umax32(mx, (uint32_t)__shfl_xor((int)mx, 1));
      mx = umax32(mx, (uint32_t)__shfl_xor((int)mx, 2));
      mx = umax32(mx, (uint32_t)__shfl_xor((int)mx, 4));
      mx = umax32(mx, (uint32_t)__shfl_xor((int)mx, 8));
      if (l15 == rnd) cand[e_loc][wave * 12 + rnd] = mx;
      const bool pop = (cur == mx);   // keys unique (t embedded) -> one lane pops
      s[r][0] = pop ? s[r][1] : s[r][0];
      s[r][1] = pop ? s[r][2] : s[r][1];
      s[r][2] = pop ? s[r][3] : s[r][2];
      s[r][3] = pop ? s[r][4] : s[r][3];
      s[r][4] = pop ? s[r][5] : s[r][4];
      s[r][5] = pop ? s[r][6] : s[r][5];
      s[r][6] = pop ? 0u      : s[r][6];
    }
  }
  __syncthreads();   // the only block-wide barrier

  // ---- per expert (4 per wave): f64 rescore of 48 candidates, top-8, gather ----
  #pragma unroll 1
  for (int el = 0; el < 4; ++el) {
    const int e_loc = wave * 4 + el;
    const int e     = eg * 16 + e_loc;
    const bool alive = lane < 48;
    uint32_t myT = 2047;
    double v = -1e300;
    if (alive) {
      uint32_t key = cand[e_loc][lane];
      myT = 2047u - (key & 2047u);
      const float* xr = x + ((size_t)b * Tt + myT) * Dd;
      const float* gr = gate_w + (size_t)e * Dd;
      double a = 0.0;
      #pragma unroll
      for (int d = 0; d < Dd; ++d) a += (double)xr[d] * (double)gr[d];
      v = a + (double)gumbel[((size_t)b * Ee + e) * Tt + myT];
    }
    uint32_t ti = alive ? myT : 0xFFFFu;
    uint32_t ord[8];
    #pragma unroll
    for (int k = 0; k < 8; ++k) {
      double bv = v; uint32_t bt = ti;
      #pragma unroll
      for (int off = 1; off < 64; off <<= 1) {
        double   ov = __shfl_xor(bv, off);
        uint32_t ot = (uint32_t)__shfl_xor((int)bt, off);
        if (ov > bv || (ov == bv && ot < bt)) { bv = ov; bt = ot; }
      }
      ord[k] = bt;           // uniform across lanes
      if (ti == bt) v = -1e300;
    }

    // gather: wave writes inp[b][e][0..255] (8 tokens x 32 feats, bf16)
    const int kk = lane >> 3, sub = lane & 7;
    uint32_t tk = ord[0];
    #pragma unroll
    for (int qq = 1; qq < 8; ++qq) tk = (kk == qq) ? ord[qq] : tk;
    const float* xs = x + ((size_t)b * Tt + tk) * Dd + sub * 4;
    f32x4 xv = *(const f32x4*)xs;
    uint32_t p0 = f2bf(xv[0]) | (f2bf(xv[1]) << 16);
    uint32_t p1 = f2bf(xv[2]) | (f2bf(xv[3]) << 16);
    uint32_t* dst = (uint32_t*)inp + ((((size_t)b * Ee + e) * 256) + kk * 32 + sub * 4) / 2;
    dst[0] = p0; dst[1] = p1;
  }
}

// ---------------------------------------------------------------------------
// Kernel B: grouped per-expert GEMM  out[b,e,:] = inp[b,e,:] . W[e]^T + bias
// 128x128 tile, K=256 in 4 steps, bf16 MFMA, W converted f32->bf16 in staging.
// XCD-aware decode: expert e's 32 blocks all land on XCD e/8 -> W slices hit L2.
// ---------------------------------------------------------------------------
__global__ __launch_bounds__(256) void kB_gemm(
    const uint16_t* __restrict__ inp,      // [B,E,256] bf16 bits
    const float* __restrict__ expert_w,    // [E,OUT,256]
    const float* __restrict__ expert_b,    // [E,OUT]
    float* __restrict__ out)               // [B,E,OUT]
{
  const int bid = blockIdx.x;                // 2048 blocks
  const int xcd = bid & 7;
  const int idx = bid >> 3;                  // 0..255
  const int e   = xcd * 8 + (idx >> 5);      // 8 experts per XCD
  const int rem = idx & 31;
  const int mb  = rem >> 3;
  const int nb  = rem & 7;
  const int b0 = mb * 128;
  const int o0 = nb * 128;
  const int tid  = threadIdx.x;
  const int wave = tid >> 6;
  const int lane = tid & 63;
  const int l15 = lane & 15, l4 = lane >> 4;
  const int wm = (wave & 1) * 64;
  const int wn = (wave >> 1) * 64;

  __shared__ __attribute__((aligned(16))) uint32_t Al[128 * 32]; // [m][64 bf16] swizzled
  __shared__ __attribute__((aligned(16))) uint32_t Wl[128 * 32]; // [o][64 bf16] swizzled

  f32x4 acc[4][4];
  #pragma unroll
  for (int i = 0; i < 4; ++i)
    #pragma unroll
    for (int j = 0; j < 4; ++j) acc[i][j] = (f32x4){0.f, 0.f, 0.f, 0.f};

  for (int ks = 0; ks < 4; ++ks) {
    // stage A (already bf16): 128 rows x 64k
    #pragma unroll
    for (int i = 0; i < 4; ++i) {
      int gi = tid + i * 256;
      int m = gi >> 3, qq = gi & 7;
      const uint4v* src = (const uint4v*)(inp + ((size_t)(b0 + m) * Ee + e) * 256 + ks * 64 + qq * 8);
      *(uint4v*)&Al[m * 32 + ((qq ^ (m & 7)) * 4)] = *src;
    }
    // stage W with f32 -> bf16 conversion
    #pragma unroll
    for (int i = 0; i < 4; ++i) {
      int gi = tid + i * 256;
      int o = gi >> 3, qq = gi & 7;
      const float* src = expert_w + ((size_t)e * OUTn + o0 + o) * 256 + ks * 64 + qq * 8;
      f32x4 w0 = *(const f32x4*)src;
      f32x4 w1 = *(const f32x4*)(src + 4);
      uint4v v;
      v[0] = f2bf(w0[0]) | (f2bf(w0[1]) << 16);
      v[1] = f2bf(w0[2]) | (f2bf(w0[3]) << 16);
      v[2] = f2bf(w1[0]) | (f2bf(w1[1]) << 16);
      v[3] = f2bf(w1[2]) | (f2bf(w1[3]) << 16);
      *(uint4v*)&Wl[o * 32 + ((qq ^ (o & 7)) * 4)] = v;
    }
    __syncthreads();

    short8 af[4][2], bf[4][2];
    #pragma unroll
    for (int mf = 0; mf < 4; ++mf)
      #pragma unroll
      for (int kb = 0; kb < 2; ++kb) {
        int row = wm + mf * 16 + l15;
        int g = kb * 4 + l4;
        af[mf][kb] = *(const short8*)&Al[row * 32 + ((g ^ (row & 7)) * 4)];
      }
    #pragma unroll
    for (int nf = 0; nf < 4; ++nf)
      #pragma unroll
      for (int kb = 0; kb < 2; ++kb) {
        int row = wn + nf * 16 + l15;
        int g = kb * 4 + l4;
        bf[nf][kb] = *(const short8*)&Wl[row * 32 + ((g ^ (row & 7)) * 4)];
      }
    #pragma unroll
    for (int mf = 0; mf < 4; ++mf)
      #pragma unroll
      for (int nf = 0; nf < 4; ++nf)
        #pragma unroll
        for (int kb = 0; kb < 2; ++kb)
          acc[mf][nf] = __builtin_amdgcn_mfma_f32_16x16x32_bf16(af[mf][kb], bf[nf][kb], acc[mf][nf], 0, 0, 0);
    __syncthreads();
  }

  // epilogue: D col = lane&15 -> o, row = (lane>>4)*4+reg -> b-row
  #pragma unroll
  for (int nf = 0; nf < 4; ++nf) {
    const int ocol = o0 + wn + nf * 16 + l15;
    const float bias = expert_b[(size_t)e * OUTn + ocol];
    #pragma unroll
    for (int mf = 0; mf < 4; ++mf) {
      #pragma unroll
      for (int reg = 0; reg < 4; ++reg) {
        const int mrow = b0 + wm + mf * 16 + l4 * 4 + reg;
        out[((size_t)mrow * Ee + e) * OUTn + ocol] = acc[mf][nf][reg] + bias;
      }
    }
  }
}

extern "C" void kernel_launch(void* const* d_in, const int* in_sizes, int n_in,
                              void* d_out, int out_size, void* d_ws, size_t ws_size,
                              hipStream_t stream) {
  const float* x        = (const float*)d_in[0];
  const float* gate_w   = (const float*)d_in[1];
  // d_in[2] = gate_b: constant per expert -> cannot change per-(b,e) top-k
  // ordering over tokens (and is zeros); values are never used downstream.
  const float* expert_w = (const float*)d_in[3];
  const float* expert_b = (const float*)d_in[4];
  const float* gumbel   = (const float*)d_in[5];

  uint16_t* inp = (uint16_t*)d_ws;   // 512*64*256*2 = 16.8 MB

  kA_select<<<2048, 256, 0, stream>>>(x, gate_w, gumbel, inp);
  kB_gemm<<<2048, 256, 0, stream>>>(inp, expert_w, expert_b, (float*)d_out);
}